// Round 1
// baseline (1910.158 us; speedup 1.0000x reference)
//
#include <hip/hip_runtime.h>
#include <cstdint>
#include <cmath>

#define B_    64
#define K_    4096
#define DIM_  50257
#define DIMP_ 50688      // 99*512, padded (pad logged to 0)
#define KNN_  8
#define NSEG_ 4
#define SEGD_ 12800      // 25 superblocks of 512 (last seg: 11857 -> 24 sb)
#define SB_   512
#define ROWS_ 16         // k-rows per workgroup
#define LN2_  0.6931471805599453

// ---------------- kernel A: LT[b][d] = log2(logits[b][d]), zero-padded ----
__global__ void log_kernel(const float* __restrict__ logits, float* __restrict__ LT) {
    int d = blockIdx.x * 256 + threadIdx.x;     // 0..DIMP-1
    int b = blockIdx.y;
    float v = 0.0f;
    if (d < DIM_) v = __log2f(logits[(size_t)b * DIM_ + d]);
    LT[(size_t)b * DIMP_ + d] = v;
}

// ---------------- kernel B: the big pass -----------------------------------
// grid = 1024 blocks (256 ktiles x 4 d-segments, XCD-swizzled), block = 1024.
// Each block: 16 k-rows x 64 b-cols over one d-segment.
// Wave wv (0..15) owns b-chunk [wv*4, wv*4+4); acc[4][16] in registers.
__global__ __launch_bounds__(1024) void main_kernel(
        const float* __restrict__ A, const float* __restrict__ LT,
        float* __restrict__ Spart, float* __restrict__ t1part) {
    __shared__ float As[ROWS_ * SB_];   // 32 KB

    const int t    = threadIdx.x;
    const int lane = t & 63;
    const int wv   = __builtin_amdgcn_readfirstlane(t) >> 6;   // wave id 0..15 (SGPR)

    // XCD-aware swizzle: all blocks on an XCD share one d-segment -> L stays in that XCD's L2
    const int wg   = blockIdx.x;        // 0..1023
    const int xcd  = wg & 7;
    const int y    = wg >> 3;           // 0..127
    const int seg  = xcd & 3;
    const int ktile = ((xcd >> 2) << 7) + y;   // 0..255, bijective
    const int kbase = ktile * ROWS_;
    const int d0    = seg * SEGD_;
    const int dend  = min(d0 + SEGD_, DIM_);

    float acc[4][16];
#pragma unroll
    for (int j = 0; j < 4; ++j)
#pragma unroll
        for (int r = 0; r < 16; ++r) acc[j][r] = 0.0f;
    float t1a[8];
#pragma unroll
    for (int j = 0; j < 8; ++j) t1a[j] = 0.0f;

    const int th = t >> 9;     // 0/1
    const int tl = t & 511;
    const float* LTw = LT + (size_t)(wv * 4) * DIMP_;

    for (int ds = d0; ds < dend; ds += SB_) {
        // ---- stage A tile to LDS; compute a*log2(a) exactly once per element
#pragma unroll
        for (int j = 0; j < 8; ++j) {
            const int row = 2 * j + th;
            const int d   = ds + tl;
            float a = (d < DIM_) ? A[(size_t)(kbase + row) * DIM_ + d] : 1.0f; // pad: 1*log2(1)=0, 1*Lpad(0)=0
            t1a[j] = fmaf(a, __log2f(a), t1a[j]);
            As[row * SB_ + tl] = a;
        }
        __syncthreads();

        // ---- 8 blocks of 64 d; 64 FMAs per block per wave
        const float* LTd = LTw + ds;
#pragma unroll 2
        for (int blk = 0; blk < 8; ++blk) {
            const int dd = blk * 64 + lane;
            float av[16];
#pragma unroll
            for (int r = 0; r < 16; ++r) av[r] = As[r * SB_ + dd];   // stride-1 across lanes: conflict-free
#pragma unroll
            for (int j = 0; j < 4; ++j) {
                const float Lv = LTd[(size_t)j * DIMP_ + dd];        // L2-resident (XCD-pinned)
#pragma unroll
                for (int r = 0; r < 16; ++r) acc[j][r] = fmaf(av[r], Lv, acc[j][r]);
            }
        }
        __syncthreads();
    }

    // ---- reduce acc over 64 lanes; lane (j*16+r) collects its value -> one coalesced-ish store
    float sval = 0.0f;
#pragma unroll
    for (int j = 0; j < 4; ++j) {
#pragma unroll
        for (int r = 0; r < 16; ++r) {
            float v = acc[j][r];
#pragma unroll
            for (int m = 32; m > 0; m >>= 1) v += __shfl_xor(v, m, 64);
            if (lane == (j * 16 + r)) sval = v;
        }
    }
    {
        const int j = lane >> 4, r = lane & 15;
        Spart[((size_t)(kbase + r) * 64 + (wv * 4 + j)) * NSEG_ + seg] = sval;
    }

    // ---- t1 partial reduce via LDS (reuse As)
    __syncthreads();
#pragma unroll
    for (int j = 0; j < 8; ++j) {
        const int row = 2 * j + th;
        As[row * SB_ + tl] = t1a[j];
    }
    __syncthreads();
    {
        float s = 0.0f;
#pragma unroll
        for (int m = 0; m < 8; ++m) s += As[wv * SB_ + m * 64 + lane];
#pragma unroll
        for (int m = 32; m > 0; m >>= 1) s += __shfl_xor(s, m, 64);
        if (lane == 0) t1part[(size_t)(kbase + wv) * NSEG_ + seg] = s;
    }
}

// ---------------- kernel C1: t1 segment combine (f64) ----------------------
__global__ void t1sum_kernel(const float* __restrict__ t1part, double* __restrict__ t1d) {
    int k = blockIdx.x * 256 + threadIdx.x;
    if (k < K_) {
        double s = 0.0;
        for (int j = 0; j < NSEG_; ++j) s += (double)t1part[k * NSEG_ + j];
        t1d[k] = s;
    }
}

// ---------------- kernel C2: scaled_dists[b][k] -----------------------------
__global__ void dist_kernel(const float* __restrict__ Spart, const double* __restrict__ t1d,
                            float* __restrict__ scaled) {
    int tid = blockIdx.x * 256 + threadIdx.x;   // B*K threads
    int b = tid >> 12;
    int k = tid & 4095;
    const float4 sp = *(const float4*)&Spart[((size_t)k * 64 + b) * NSEG_];
    double s = (double)sp.x + (double)sp.y + (double)sp.z + (double)sp.w;
    const double C = -(1.0 / 0.05) * LN2_ / (double)DIM_;   // fold ln2 + mean + (-1/T)
    scaled[(size_t)b * K_ + k] = (float)(C * (t1d[k] - s));
}

// ---------------- kernel D: per-row top-8 + softmax + class scatter ---------
__global__ void topk_kernel(const float* __restrict__ scaled, const int* __restrict__ label,
                            float* __restrict__ out) {
    __shared__ float vals[K_];
    __shared__ float rv[256];
    __shared__ int   ri[256];
    __shared__ float topv[KNN_];
    __shared__ int   topi[KNN_];
    const int b = blockIdx.x, t = threadIdx.x;
    for (int i = t; i < K_; i += 256) vals[i] = scaled[(size_t)b * K_ + i];
    __syncthreads();
    for (int it = 0; it < KNN_; ++it) {
        float bv = -INFINITY; int bi = K_;
        for (int i = t; i < K_; i += 256) {      // ascending: first max = lowest idx (tie rule)
            float v = vals[i];
            if (v > bv) { bv = v; bi = i; }
        }
        rv[t] = bv; ri[t] = bi;
        __syncthreads();
        for (int s = 128; s > 0; s >>= 1) {
            if (t < s) {
                float v2 = rv[t + s]; int i2 = ri[t + s];
                if (v2 > rv[t] || (v2 == rv[t] && i2 < ri[t])) { rv[t] = v2; ri[t] = i2; }
            }
            __syncthreads();
        }
        if (t == 0) { topv[it] = rv[0]; topi[it] = ri[0]; vals[ri[0]] = -INFINITY; }
        __syncthreads();
    }
    if (t == 0) {
        const float m = topv[0];
        float w[KNN_], s = 0.0f;
        for (int i = 0; i < KNN_; ++i) { w[i] = expf(topv[i] - m); s += w[i]; }
        float p0 = 0.0f, p1 = 0.0f;
        for (int i = 0; i < KNN_; ++i) {
            const float ww = w[i] / s;
            if (label[topi[i]] != 0) p1 += ww; else p0 += ww;
        }
        out[b * 2 + 0] = p0;
        out[b * 2 + 1] = p1;
    }
}

// ---------------- launch -----------------------------------------------------
extern "C" void kernel_launch(void* const* d_in, const int* in_sizes, int n_in,
                              void* d_out, int out_size, void* d_ws, size_t ws_size,
                              hipStream_t stream) {
    const float* logits = (const float*)d_in[0];
    const float* A      = (const float*)d_in[1];    // queue_anchor
    const int*   label  = (const int*)d_in[2];      // jax default x64-off -> int32
    float*       out    = (float*)d_out;

    char* ws = (char*)d_ws;
    // offsets (all 256B-aligned)
    float*  LT     = (float*)(ws);                          // 50688*64*4  = 12,976,128
    float*  Spart  = (float*)(ws + 12976128);               // 4096*64*4*4 =  4,194,304
    float*  t1part = (float*)(ws + 12976128 + 4194304);     // 4096*4*4    =     65,536
    double* t1d    = (double*)(ws + 12976128 + 4194304 + 65536);          //     32,768
    float*  scaled = (float*)(ws + 12976128 + 4194304 + 65536 + 32768);   //  1,048,576
    // total ~18.3 MB of workspace

    dim3 gA(DIMP_ / 256, B_);
    log_kernel<<<gA, 256, 0, stream>>>(logits, LT);

    main_kernel<<<1024, 1024, 0, stream>>>(A, LT, Spart, t1part);

    t1sum_kernel<<<K_ / 256, 256, 0, stream>>>(t1part, t1d);

    dist_kernel<<<(B_ * K_) / 256, 256, 0, stream>>>(Spart, t1d, scaled);

    topk_kernel<<<B_, 256, 0, stream>>>(scaled, label, out);
}